// Round 5
// baseline (532.141 us; speedup 1.0000x reference)
//
#include <hip/hip_runtime.h>

// ChebConv B=4, N=4096, C=128, K=3 fp32.
// Round 5 = Round 4 (passing) + occupancy fixes:
//   - prep_cast: 256 -> 2048 blocks (1/CU -> 8/CU). Streaming kernel was
//     latency-starved at 4 waves/CU (~150us vs 64us HBM floor).
//   - mfma_part: split-K 4 -> 8 (512 -> 1024 blocks, ~3/CU resident) for more
//     cross-block overlap at barriers. Cpart now 8 slices (67MB).
//   - reduce_z1/z2 sum 8 partials.
// Proven pieces unchanged: MFMA tile/fragment mappings, granule-XOR LDS
// swizzle, scrambled-view gemm_final (chunk = (m*384+k)>>19).
// ws: adjB 134.2MB | Cpart 67.1MB | Zf 16.8MB | xTb 4MB | z1Tb 4MB | deg | Wt

#define NN 4096
#define CF 128
#define NC (NN * CF)
#define LRC 0.9999995f

typedef __attribute__((ext_vector_type(8))) short bf16x8;
typedef __attribute__((ext_vector_type(4))) float f32x4;

__device__ __forceinline__ unsigned short f2b(float f) {
    unsigned u = __float_as_uint(f);
    return (unsigned short)((u + 0x7FFFu + ((u >> 16) & 1u)) >> 16);  // RNE
}

// ---- one fp32 pass over adj: exact degree + bf16 cast. 2048 blocks (8/CU). ----
__global__ __launch_bounds__(256) void prep_cast(const float* __restrict__ adj,
                                                 unsigned short* __restrict__ adjB,
                                                 float* __restrict__ deg) {
    const int b = blockIdx.z;
    const size_t base = (size_t)b * NN * NN;
    const int n0 = blockIdx.x * 1024;     // 4 col groups
    const int m0 = blockIdx.y * 32;       // 128 row slabs
    const int t = threadIdx.x;
    float4 s = make_float4(0.f, 0.f, 0.f, 0.f);
    const size_t col = (size_t)(n0 + t * 4);
    for (int m = 0; m < 32; ++m) {
        const size_t idx = base + (size_t)(m0 + m) * NN + col;
        const float4 v = *(const float4*)&adj[idx];
        s.x += v.x; s.y += v.y; s.z += v.z; s.w += v.w;
        ushort4 o;
        o.x = f2b(v.x); o.y = f2b(v.y); o.z = f2b(v.z); o.w = f2b(v.w);
        *(ushort4*)&adjB[idx] = o;
    }
    float* dp = deg + b * NN + n0 + t * 4;
    atomicAdd(dp + 0, s.x);
    atomicAdd(dp + 1, s.y);
    atomicAdd(dp + 2, s.z);
    atomicAdd(dp + 3, s.w);
}

// ---- x -> xT bf16 [B][128 feat][4096 node] ----
__global__ __launch_bounds__(256) void transpose_x(const float* __restrict__ x,
                                                   unsigned short* __restrict__ xTb) {
    __shared__ float tile[64][65];
    const int b = blockIdx.z, m0 = blockIdx.x * 64, n0 = blockIdx.y * 64;
    const int t = threadIdx.x;
    const int c = t & 63, r4 = t >> 6;
    const float* xb = x + (size_t)b * NC;
#pragma unroll
    for (int i = 0; i < 16; ++i) {
        int r = i * 4 + r4;
        tile[r][c] = xb[(size_t)(m0 + r) * CF + n0 + c];
    }
    __syncthreads();
    unsigned short* xo = xTb + (size_t)b * NC + (size_t)n0 * NN + m0;
#pragma unroll
    for (int i = 0; i < 16; ++i) {
        int r = i * 4 + r4;
        xo[(size_t)r * NN + c] = f2b(tile[c][r]);
    }
}

__global__ __launch_bounds__(256) void wt_kernel(const float* __restrict__ W,
                                                 float* __restrict__ Wt) {
    const int idx = blockIdx.x * 256 + threadIdx.x;  // < 128*384
    const int o = idx / 384;
    const int f = idx % 384;
    Wt[f * 128 + o] = W[idx];
}

// ---- split-K=8 MFMA GEMM: Cpart[b][kc] = adjB[m, kc-chunk] @ z[kc-chunk, n] ----
// grid (32 m-tiles, 8 k-chunks, 4 batches) = 1024 blocks, 256 thr.
__global__ __launch_bounds__(256, 2) void mfma_part(
    const unsigned short* __restrict__ adjB,
    const unsigned short* __restrict__ Bt,   // bf16 zT [B][128][4096]
    float* __restrict__ Cpart)
{
    const int t = threadIdx.x;
    const int w = t >> 6, lane = t & 63, q = lane >> 4, l16 = lane & 15;
    const int wm = w & 1, wn = w >> 1;
    const int m0 = blockIdx.x * 128;
    const int kc = blockIdx.y;
    const int b  = blockIdx.z;

    __shared__ __align__(16) short As[8192];   // 16 KB
    __shared__ __align__(16) short Bs[8192];   // 16 KB

    const int g  = t & 7;          // k-granule (8 shorts = 16 B)
    const int r0 = t >> 3;         // row 0..31 (+32i)

    const unsigned short* ap = adjB + (size_t)b * NN * NN + (size_t)kc * 512 + g * 8;
    const unsigned short* bp = Bt   + (size_t)b * NC      + (size_t)kc * 512 + g * 8;

    f32x4 acc[4][4];
#pragma unroll
    for (int i = 0; i < 4; ++i)
#pragma unroll
        for (int j = 0; j < 4; ++j) acc[i][j] = (f32x4)0.f;

    bf16x8 ar[4], br[4];
#pragma unroll
    for (int i = 0; i < 4; ++i) {
        const int r = r0 + i * 32;
        ar[i] = *(const bf16x8*)(ap + (size_t)(m0 + r) * NN);
        br[i] = *(const bf16x8*)(bp + (size_t)r * NN);
    }

    for (int it = 0; it < 8; ++it) {
        __syncthreads();   // previous iteration's frag reads complete
#pragma unroll
        for (int i = 0; i < 4; ++i) {
            const int r = r0 + i * 32;
            const int slot = (g ^ (r & 7)) << 3;
            *(bf16x8*)&As[r * 64 + slot] = ar[i];
            *(bf16x8*)&Bs[r * 64 + slot] = br[i];
        }
        __syncthreads();
        if (it < 7) {
            const int kof = (it + 1) * 64;
#pragma unroll
            for (int i = 0; i < 4; ++i) {
                const int r = r0 + i * 32;
                ar[i] = *(const bf16x8*)(ap + (size_t)(m0 + r) * NN + kof);
                br[i] = *(const bf16x8*)(bp + (size_t)r * NN + kof);
            }
        }
#pragma unroll
        for (int kh = 0; kh < 2; ++kh) {
            bf16x8 af[4], bf[4];
#pragma unroll
            for (int i = 0; i < 4; ++i) {
                const int ml = wm * 64 + i * 16 + l16;
                af[i] = *(const bf16x8*)&As[ml * 64 + ((((kh << 2) + q) ^ (ml & 7)) << 3)];
                const int nl = wn * 64 + i * 16 + l16;
                bf[i] = *(const bf16x8*)&Bs[nl * 64 + ((((kh << 2) + q) ^ (nl & 7)) << 3)];
            }
#pragma unroll
            for (int i = 0; i < 4; ++i)
#pragma unroll
                for (int j = 0; j < 4; ++j)
                    acc[i][j] = __builtin_amdgcn_mfma_f32_16x16x32_bf16(
                        af[i], bf[j], acc[i][j], 0, 0, 0);
        }
    }

    // store fp32 partials: C/D layout col=l16, row=q*4+reg
    float* Cb = Cpart + (size_t)(b * 8 + kc) * NC;
#pragma unroll
    for (int i = 0; i < 4; ++i) {
        const int mrow = m0 + wm * 64 + i * 16 + q * 4;
#pragma unroll
        for (int j = 0; j < 4; ++j) {
            const int n = wn * 64 + j * 16 + l16;
#pragma unroll
            for (int r = 0; r < 4; ++r)
                Cb[(size_t)(mrow + r) * CF + n] = acc[i][j][r];
        }
    }
}

// ---- reduce 8 partials + Z1 epilogue + transposed bf16 z1 ----
__global__ __launch_bounds__(256) void reduce_z1(const float* __restrict__ Cpart,
                                                 const float* __restrict__ x,
                                                 const float* __restrict__ deg,
                                                 float* __restrict__ Zf,
                                                 unsigned short* __restrict__ z1Tb) {
    __shared__ unsigned short sh[64][68];
    const int b = blockIdx.z, m0 = blockIdx.x * 64, n0 = blockIdx.y * 64;
    const int t = threadIdx.x;
    const int r0 = (t >> 4) * 4, c0 = (t & 15) * 4;
    const float* degb = deg + b * NN;
    const float* xb = x + (size_t)b * NC;
    float* Zf1 = Zf + (size_t)b * 2 * NC;
#pragma unroll
    for (int rr = 0; rr < 4; ++rr) {
        const int m = m0 + r0 + rr;
        f32x4 s = (f32x4)0.f;
#pragma unroll
        for (int kc = 0; kc < 8; ++kc)
            s += *(const f32x4*)&Cpart[(size_t)(b * 8 + kc) * NC + (size_t)m * CF + n0 + c0];
        const f32x4 xv = *(const f32x4*)&xb[(size_t)m * CF + n0 + c0];
        const float d = degb[m];
        f32x4 z;
#pragma unroll
        for (int cc = 0; cc < 4; ++cc) z[cc] = LRC * (d * xv[cc] - s[cc]) - xv[cc];
        *(f32x4*)&Zf1[(size_t)m * CF + n0 + c0] = z;
#pragma unroll
        for (int cc = 0; cc < 4; ++cc) sh[c0 + cc][r0 + rr] = f2b(z[cc]);
    }
    __syncthreads();
    unsigned short* zo = z1Tb + (size_t)b * NC + (size_t)n0 * NN + m0;
    const int nl = t >> 2;
#pragma unroll
    for (int i = 0; i < 4; ++i) {
        const int ml = ((t & 3) + i * 4) * 4;
        ushort4 v;
        v.x = sh[nl][ml]; v.y = sh[nl][ml + 1]; v.z = sh[nl][ml + 2]; v.w = sh[nl][ml + 3];
        *(ushort4*)&zo[(size_t)nl * NN + ml] = v;
    }
}

// ---- reduce 8 partials + Z2 epilogue ----
__global__ __launch_bounds__(256) void reduce_z2(const float* __restrict__ Cpart,
                                                 const float* __restrict__ x,
                                                 const float* __restrict__ deg,
                                                 float* __restrict__ Zf) {
    const size_t gidx = (size_t)blockIdx.x * 256 + threadIdx.x;   // over 4*NC/4 vec4s
    const int b = (int)(gidx / (NC / 4));
    const size_t rem = gidx % (NC / 4);
    const int m = (int)(rem / (CF / 4));
    const int c0 = (int)(rem % (CF / 4)) * 4;
    f32x4 s = (f32x4)0.f;
#pragma unroll
    for (int kc = 0; kc < 8; ++kc)
        s += *(const f32x4*)&Cpart[(size_t)(b * 8 + kc) * NC + (size_t)m * CF + c0];
    const f32x4 xv = *(const f32x4*)&x[(size_t)b * NC + (size_t)m * CF + c0];
    const f32x4 z1 = *(const f32x4*)&Zf[(size_t)b * 2 * NC + (size_t)m * CF + c0];
    const float d = deg[b * NN + m];
    f32x4 z;
#pragma unroll
    for (int cc = 0; cc < 4; ++cc)
        z[cc] = 2.f * (LRC * (d * z1[cc] - s[cc]) - z1[cc]) - xv[cc];
    *(f32x4*)&Zf[(size_t)b * 2 * NC + NC + (size_t)m * CF + c0] = z;
}

// ---- final fp32 GEMM over the TRUE scrambled view ----
// view row m, col f -> flat G = m*384+f over [x|z1|z2] (each 2^19 elems):
//   chunk = G>>19, rem = G & (2^19-1); float4 at f%4==0 never crosses a boundary.
__global__ __launch_bounds__(256) void gemm_final(const float* __restrict__ x,
                                                  const float* __restrict__ Zf,
                                                  const float* __restrict__ Wt,
                                                  float* __restrict__ out) {
    const int b = blockIdx.z;
    float* Cb = out + (size_t)b * NC;

    const int t = threadIdx.x;
    const int tx = t & 15, ty = t >> 4;
    const int m0 = blockIdx.y * 64, n0 = blockIdx.x * 64;

    __shared__ float Asm[16][68];
    __shared__ float Bsm[16][64];

    const int arow = t >> 2;
    const int ak4 = (t & 3) << 2;
    const int bk = t >> 4;
    const int bn4 = (t & 15) << 2;

    const float* xb = x + (size_t)b * NC;

    float4 acc[4];
    acc[0] = acc[1] = acc[2] = acc[3] = make_float4(0.f, 0.f, 0.f, 0.f);

    const float* bptr = Wt + (size_t)bk * 128 + n0 + bn4;

    auto aload = [&](int k) -> float4 {
        const unsigned G = (unsigned)(m0 + arow) * 384u + (unsigned)k;
        const int chunk = (int)(G >> 19);
        const unsigned rem = G & 524287u;
        const float* src = (chunk == 0) ? xb : (Zf + (size_t)(b * 2 + (chunk - 1)) * NC);
        return *(const float4*)&src[rem];
    };

    float4 av = aload(ak4);
    float4 bv = *(const float4*)bptr;

    for (int k0 = 0; k0 < 384; k0 += 16) {
        __syncthreads();
        Asm[ak4 + 0][arow] = av.x;
        Asm[ak4 + 1][arow] = av.y;
        Asm[ak4 + 2][arow] = av.z;
        Asm[ak4 + 3][arow] = av.w;
        *(float4*)&Bsm[bk][bn4] = bv;
        __syncthreads();
        if (k0 + 16 < 384) {
            av = aload(k0 + 16 + ak4);
            bv = *(const float4*)(bptr + (size_t)(k0 + 16) * 128);
        }
#pragma unroll
        for (int kk = 0; kk < 16; ++kk) {
            const float4 a = *(const float4*)&Asm[kk][ty << 2];
            const float4 bb = *(const float4*)&Bsm[kk][tx << 2];
            acc[0].x += a.x * bb.x; acc[0].y += a.x * bb.y; acc[0].z += a.x * bb.z; acc[0].w += a.x * bb.w;
            acc[1].x += a.y * bb.x; acc[1].y += a.y * bb.y; acc[1].z += a.y * bb.z; acc[1].w += a.y * bb.w;
            acc[2].x += a.z * bb.x; acc[2].y += a.z * bb.y; acc[2].z += a.z * bb.z; acc[2].w += a.z * bb.w;
            acc[3].x += a.w * bb.x; acc[3].y += a.w * bb.y; acc[3].z += a.w * bb.z; acc[3].w += a.w * bb.w;
        }
    }

    const int ncol = n0 + (tx << 2);
#pragma unroll
    for (int i = 0; i < 4; ++i) {
        const int m = m0 + (ty << 2) + i;
        *(float4*)&Cb[(size_t)m * 128 + ncol] = acc[i];
    }
}

extern "C" void kernel_launch(void* const* d_in, const int* in_sizes, int n_in,
                              void* d_out, int out_size, void* d_ws, size_t ws_size,
                              hipStream_t stream) {
    const float* x   = (const float*)d_in[0];   // [4, 4096, 128]
    const float* adj = (const float*)d_in[1];   // [4, 4096, 4096]
    const float* W   = (const float*)d_in[2];   // [128, 384]
    float* out = (float*)d_out;

    char* ws = (char*)d_ws;
    unsigned short* adjB = (unsigned short*)ws;                     // 134,217,728 B
    float* Cpart         = (float*)(ws + 134217728u);               //  67,108,864 B (8 slices)
    float* Zf            = (float*)(ws + 201326592u);               //  16,777,216 B [b][z1,z2][4096][128]
    unsigned short* xTb  = (unsigned short*)(ws + 218103808u);      //   4,194,304 B
    unsigned short* z1Tb = (unsigned short*)(ws + 222298112u);      //   4,194,304 B
    float* deg           = (float*)(ws + 226492416u);               //      65,536 B
    float* Wt            = (float*)(ws + 226557952u);               //     196,608 B

    hipMemsetAsync(deg, 0, 4 * NN * sizeof(float), stream);
    prep_cast<<<dim3(4, 128, 4), 256, 0, stream>>>(adj, adjB, deg);
    transpose_x<<<dim3(64, 2, 4), 256, 0, stream>>>(x, xTb);
    wt_kernel<<<192, 256, 0, stream>>>(W, Wt);

    // Z1 = lr*(deg*x - adj@x) - x
    mfma_part<<<dim3(32, 8, 4), 256, 0, stream>>>(adjB, xTb, Cpart);
    reduce_z1<<<dim3(64, 2, 4), 256, 0, stream>>>(Cpart, x, deg, Zf, z1Tb);

    // Z2 = 2*(lr*(deg*z1 - adj@z1) - z1) - x
    mfma_part<<<dim3(32, 8, 4), 256, 0, stream>>>(adjB, z1Tb, Cpart);
    reduce_z2<<<2048, 256, 0, stream>>>(Cpart, x, deg, Zf);

    // out = [x | z1 | z2] (scrambled view) @ Wt
    gemm_final<<<dim3(2, 64, 4), 256, 0, stream>>>(x, Zf, Wt, out);
}